// Round 21
// baseline (71.014 us; speedup 1.0000x reference)
//
#include <hip/hip_runtime.h>
#include <hip/hip_bf16.h>

#define HW 9216
#define NPIX 18432

typedef __attribute__((ext_vector_type(8))) short short8v;
typedef __attribute__((ext_vector_type(4))) float f32x4;

__device__ __forceinline__ float bf2f(short s) {
    union { unsigned u; float f; } c;
    c.u = ((unsigned)(unsigned short)s) << 16;
    return c.f;
}
__device__ __forceinline__ unsigned short f2bfbits(float f) {
    __hip_bfloat16 h = __float2bfloat16(f);
    return *reinterpret_cast<unsigned short*>(&h);
}

// bijective XCD swizzle for 576-block grids (576 = 8 * 72)
__device__ __forceinline__ int xcd_swz576(int bid) {
    return (bid & 7) * 72 + (bid >> 3);
}

// ---------------- transpose (z<4, ushort4 stores) + weight prep / border zero (z==4) ----------------
__global__ void transprep_k(const float* __restrict__ past, const float* __restrict__ curr,
                            const float* __restrict__ w_fuse, const float* __restrict__ w_reduce,
                            const float* __restrict__ w_v0, const float* __restrict__ w_v1,
                            __hip_bfloat16* __restrict__ curr_b,
                            __hip_bfloat16* __restrict__ featp,
                            __hip_bfloat16* __restrict__ pg,
                            __hip_bfloat16* __restrict__ wtp, __hip_bfloat16* __restrict__ wr_b,
                            __hip_bfloat16* __restrict__ wv0_b, __hip_bfloat16* __restrict__ wv1_b) {
    int z = blockIdx.z;
    if (z < 4) {
        __shared__ float tile[32][33];               // [c_local][px]
        int t = z & 1, b = z >> 1;
        const float* src = t ? curr : past;
        int p0 = blockIdx.x * 32, c0 = blockIdx.y * 32;
        for (int k = threadIdx.y; k < 32; k += 8)
            tile[k][threadIdx.x] = src[(size_t)(b * 64 + c0 + k) * HW + p0 + threadIdx.x];
        __syncthreads();
        int tid = threadIdx.y * 32 + threadIdx.x;
        int px = tid >> 3, cq = tid & 7;
        int pp = p0 + px;
        int cl = cq * 4;
        ushort4 pk;
        pk.x = f2bfbits(tile[cl + 0][px]);
        pk.y = f2bfbits(tile[cl + 1][px]);
        pk.z = f2bfbits(tile[cl + 2][px]);
        pk.w = f2bfbits(tile[cl + 3][px]);
        int c = c0 + cl;
        if (t) {
            *(ushort4*)(curr_b + ((size_t)b * HW + pp) * 64 + c) = pk;
        } else {
            int y = pp / 96, x = pp - (pp / 96) * 96;
            *(ushort4*)(featp + (((size_t)b * 98 + y + 1) * 98 + x + 1) * 192 + c) = pk;
            int g = c >> 3, cg = c & 7;
            *(ushort4*)(pg + (((size_t)b * 8 + g) * HW + pp) * 8 + cg) = pk;
        }
    } else {
        int i = (blockIdx.y * 288 + blockIdx.x) * 256 + threadIdx.y * 32 + threadIdx.x;
        if (i < 110592) {
            int j = i & 7, rest = i >> 3;
            int lm = rest & 15; rest >>= 4;
            int g = rest & 3; rest >>= 2;
            int ks = rest % 54, nt = rest / 54;
            int o = nt * 16 + lm;
            int kg = ks * 32 + g * 8 + j;
            int tap = kg / 192, c = kg - tap * 192;
            wtp[i] = __float2bfloat16(w_fuse[o * 1728 + c * 9 + tap]);
        }
        if (i < 8192) wr_b[i] = __float2bfloat16(w_reduce[i]);
        if (i < 4096) { wv0_b[i] = __float2bfloat16(w_v0[i]); wv1_b[i] = __float2bfloat16(w_v1[i]); }
        if (i < 2 * 98 * 98) {
            int pp = i % (98 * 98);
            int y = pp / 98, x = pp - y * 98;
            if (y == 0 || y == 97 || x == 0 || x == 97) {
                short8v zz = {0, 0, 0, 0, 0, 0, 0, 0};
                short8v* d = (short8v*)(featp + (size_t)i * 192);
                #pragma unroll
                for (int k = 0; k < 24; ++k) d[k] = zz;
            }
        }
    }
}

// ---------------- smooth + reduce + V convs: 32 px/block, 256 threads, coalesced writeout ----------------
__global__ __launch_bounds__(256) void smoothrv_k(const __hip_bfloat16* __restrict__ pg,
                                                  const float* __restrict__ w_smooth,
                                                  const float* __restrict__ b_smooth,
                                                  const __hip_bfloat16* __restrict__ wr_b,
                                                  const float* __restrict__ b_reduce,
                                                  const __hip_bfloat16* __restrict__ wv0_b,
                                                  const __hip_bfloat16* __restrict__ wv1_b,
                                                  const float* __restrict__ b_v0,
                                                  const float* __restrict__ b_v1,
                                                  __hip_bfloat16* __restrict__ past2_b,
                                                  __hip_bfloat16* __restrict__ v0_b,
                                                  __hip_bfloat16* __restrict__ v1_b) {
    __shared__ __hip_bfloat16 sm[32][72];
    __shared__ __hip_bfloat16 p2[32][72];
    int tid = threadIdx.x;
    int p0 = blockIdx.x * 32;                  // 32 | 9216: never crosses batch
    int bb = p0 / HW, rem0 = p0 - bb * HW;
    int wrow = tid >> 3, wc8 = (tid & 7) * 8;  // coalesced-writeout mapping (32 rows x 64 ch)

    // ---- phase A: smooth; thread = (group g, pixel px) ----
    {
        int g = tid >> 5, px = tid & 31;
        int rem = rem0 + px;
        int y = rem / 96, x = rem - y * 96;
        int gi = g < 4 ? g : g + 1;            // skip (0,0)
        int sy = gi / 3 - 1, sx = gi % 3 - 1;
        const __hip_bfloat16* base = pg + (((size_t)bb * 8 + g) * HW) * 8;
        float v[9][8];
        #pragma unroll
        for (int ky = 0; ky < 3; ++ky) {
            #pragma unroll
            for (int kx = 0; kx < 3; ++kx) {
                int yy = y + ky - 1, xx = x + kx - 1;
                int ys = yy - sy, xs = xx - sx;
                bool ok = (unsigned)yy < 96u && (unsigned)xx < 96u &&
                          (unsigned)ys < 96u && (unsigned)xs < 96u;
                int off = ok ? (ys * 96 + xs) : rem;
                short8v ld = *(const short8v*)(base + (size_t)off * 8);
                float okf = ok ? 1.f : 0.f;
                #pragma unroll
                for (int c = 0; c < 8; ++c)
                    v[ky * 3 + kx][c] = okf * bf2f(ld[c]);
            }
        }
        float acc[8];
        #pragma unroll
        for (int j = 0; j < 8; ++j) acc[j] = b_smooth[g * 8 + j];
        #pragma unroll
        for (int j = 0; j < 8; ++j) {
            const float* wp = w_smooth + (g * 8 + j) * 72;   // wave-uniform -> s_load
            #pragma unroll
            for (int c = 0; c < 8; ++c)
                #pragma unroll
                for (int t = 0; t < 9; ++t)
                    acc[j] += wp[c * 9 + t] * v[t][c];
        }
        short8v pack;
        #pragma unroll
        for (int j = 0; j < 8; ++j) {
            __hip_bfloat16 h = __float2bfloat16(acc[j]);
            pack[j] = *reinterpret_cast<short*>(&h);
        }
        *(short8v*)(&sm[px][g * 8]) = pack;
    }
    __syncthreads();

    // ---- phase B: 1x1 reduce (K=128 over [past | smooth]); 4 waves over 32px x 64ch ----
    int w = tid >> 6, lane = tid & 63;
    int mtile = w >> 1, nbase = (w & 1) * 32;
    int lm = lane & 15, g = lane >> 4;
    int o0 = nbase + lm, o1 = o0 + 16;
    f32x4 a00, a01, a10, a11;   // phase-C accumulators (declared here for scope)
    {
        f32x4 acc0 = {0, 0, 0, 0}, acc1 = {0, 0, 0, 0};
        int pixr = rem0 + mtile * 16 + lm;
        const __hip_bfloat16* b0p = wr_b + (size_t)(nbase + lm) * 128 + g * 8;
        const __hip_bfloat16* b1p = b0p + 16 * 128;
        #pragma unroll
        for (int c0 = 0; c0 < 128; c0 += 32) {
            short8v a;
            if (c0 < 64) {
                int gch = (c0 >> 3) + g;
                a = *reinterpret_cast<const short8v*>(
                        pg + (((size_t)bb * 8 + gch) * HW + pixr) * 8);
            } else {
                a = *reinterpret_cast<const short8v*>(&sm[mtile * 16 + lm][g * 8 + (c0 - 64)]);
            }
            short8v b0 = *reinterpret_cast<const short8v*>(b0p + c0);
            short8v b1 = *reinterpret_cast<const short8v*>(b1p + c0);
            acc0 = __builtin_amdgcn_mfma_f32_16x16x32_bf16(a, b0, acc0, 0, 0, 0);
            acc1 = __builtin_amdgcn_mfma_f32_16x16x32_bf16(a, b1, acc1, 0, 0, 0);
        }
        float bias0 = b_reduce[o0], bias1 = b_reduce[o1];
        #pragma unroll
        for (int r = 0; r < 4; ++r) {
            int pl = mtile * 16 + g * 4 + r;
            p2[pl][o0] = __float2bfloat16(acc0[r] + bias0);
            p2[pl][o1] = __float2bfloat16(acc1[r] + bias1);
        }
    }
    __syncthreads();

    // coalesced past2 writeout: one 16B store per thread
    *(short8v*)(past2_b + (size_t)(p0 + wrow) * 64 + wc8) = *(const short8v*)(&p2[wrow][wc8]);

    // ---- phase C: both V 1x1 convs from LDS past2 ----
    {
        a00 = (f32x4){0,0,0,0}; a01 = (f32x4){0,0,0,0};
        a10 = (f32x4){0,0,0,0}; a11 = (f32x4){0,0,0,0};
        size_t bo = (size_t)(nbase + lm) * 64 + g * 8;
        #pragma unroll
        for (int c0 = 0; c0 < 64; c0 += 32) {
            short8v a   = *reinterpret_cast<const short8v*>(&p2[mtile * 16 + lm][g * 8 + c0]);
            short8v b00 = *reinterpret_cast<const short8v*>(wv0_b + bo + c0);
            short8v b01 = *reinterpret_cast<const short8v*>(wv0_b + bo + 16 * 64 + c0);
            short8v b10 = *reinterpret_cast<const short8v*>(wv1_b + bo + c0);
            short8v b11 = *reinterpret_cast<const short8v*>(wv1_b + bo + 16 * 64 + c0);
            a00 = __builtin_amdgcn_mfma_f32_16x16x32_bf16(a, b00, a00, 0, 0, 0);
            a01 = __builtin_amdgcn_mfma_f32_16x16x32_bf16(a, b01, a01, 0, 0, 0);
            a10 = __builtin_amdgcn_mfma_f32_16x16x32_bf16(a, b10, a10, 0, 0, 0);
            a11 = __builtin_amdgcn_mfma_f32_16x16x32_bf16(a, b11, a11, 0, 0, 0);
        }
    }
    __syncthreads();   // p2 reads complete; sm free for reuse

    // v0 tile -> sm -> coalesced store
    {
        float bi0 = b_v0[o0], bi1 = b_v0[o1];
        #pragma unroll
        for (int r = 0; r < 4; ++r) {
            int pl = mtile * 16 + g * 4 + r;
            sm[pl][o0] = __float2bfloat16(a00[r] + bi0);
            sm[pl][o1] = __float2bfloat16(a01[r] + bi1);
        }
    }
    __syncthreads();
    *(short8v*)(v0_b + (size_t)(p0 + wrow) * 64 + wc8) = *(const short8v*)(&sm[wrow][wc8]);
    __syncthreads();

    // v1 tile -> sm -> coalesced store
    {
        float bi0 = b_v1[o0], bi1 = b_v1[o1];
        #pragma unroll
        for (int r = 0; r < 4; ++r) {
            int pl = mtile * 16 + g * 4 + r;
            sm[pl][o0] = __float2bfloat16(a10[r] + bi0);
            sm[pl][o1] = __float2bfloat16(a11[r] + bi1);
        }
    }
    __syncthreads();
    *(short8v*)(v1_b + (size_t)(p0 + wrow) * 64 + wc8) = *(const short8v*)(&sm[wrow][wc8]);
}

// ---------------- natten3 body: 2x16-px tile, Q in registers, exact K-tiling ----------------
template <int KS>
__device__ __forceinline__ void natten_body3(
    const __hip_bfloat16* __restrict__ q_b,
    const __hip_bfloat16* __restrict__ k_b,
    const __hip_bfloat16* __restrict__ v_b,
    const float* __restrict__ rpb,
    __hip_bfloat16* __restrict__ featp, int coff, char* smem, int blk) {
    constexpr int R = KS / 2, RW = 2 * KS - 1;
    constexpr int CW = 16 + KS - 1;
    constexpr int RU = KS + 1;
    constexpr int NPOS = RU * CW;
    constexpr int NT = (NPOS + 15) / 16;
    constexpr int NKR = NT * 16;
    constexpr int NKV = ((NPOS + 31) / 32) * 32;
    constexpr int KROW = 72;
    constexpr int VROW = NKV + 10;
    constexpr int SROW = NKR + 4;

    __hip_bfloat16* KU = (__hip_bfloat16*)smem;
    float*          S  = (float*)smem;
    __hip_bfloat16* Vt = (__hip_bfloat16*)(smem + NKR * KROW * 2);
    float*       rpb_s = (float*)((char*)Vt + 64 * VROW * 2);

    int x0 = (blk % 6) * 16;
    int rp = blk / 6;
    int b = rp / 48, yp = (rp - b * 48) * 2;
    int ymin = yp - R; ymin = ymin < 0 ? 0 : (ymin > 96 - KS ? 96 - KS : ymin);
    int c0 = x0 - R;   c0 = c0 < 0 ? 0 : (c0 > 96 - KS ? 96 - KS : c0);
    int tid = threadIdx.x;
    size_t plane = (size_t)b * HW;

    int l = tid & 63, w = tid >> 6;
    int lm = l & 15, g = l >> 4;
    int mt = w >> 2, wn = w & 3;
    int yr = yp + mt;

    const __hip_bfloat16* qp = q_b + (plane + yr * 96 + x0 + lm) * 64 + g * 8;
    short8v qa0 = *(const short8v*)qp;
    short8v qa1 = *(const short8v*)(qp + 32);

    for (int i = tid; i < RW * RW; i += 512) rpb_s[i] = rpb[i];
    for (int pos = tid >> 3; pos < NKR; pos += 64) {
        int c8 = (tid & 7) * 8;
        short8v val = {0, 0, 0, 0, 0, 0, 0, 0};
        if (pos < NPOS) {
            int i = pos / CW, j = pos - i * CW;
            int gy = ymin + i; gy = gy > 95 ? 95 : gy;
            int gx = c0 + j;   gx = gx > 95 ? 95 : gx;
            val = *(const short8v*)(k_b + (plane + gy * 96 + gx) * 64 + c8);
        }
        *(short8v*)(KU + pos * KROW + c8) = val;
    }
    for (int pos = tid >> 3; pos < NKV; pos += 64) {
        int c8 = (tid & 7) * 8;
        short8v val = {0, 0, 0, 0, 0, 0, 0, 0};
        if (pos < NPOS) {
            int i = pos / CW, j = pos - i * CW;
            int gy = ymin + i; gy = gy > 95 ? 95 : gy;
            int gx = c0 + j;   gx = gx > 95 ? 95 : gx;
            val = *(const short8v*)(v_b + (plane + gy * 96 + gx) * 64 + c8);
        }
        #pragma unroll
        for (int j = 0; j < 8; ++j)
            *((short*)Vt + (c8 + j) * VROW + pos) = val[j];
    }
    __syncthreads();                                                  // 1

    f32x4 sacc[3];
    #pragma unroll
    for (int k = 0; k < 3; ++k) {
        int t = wn + 4 * k;
        if (t < NT) {
            f32x4 acc = {0, 0, 0, 0};
            const __hip_bfloat16* kp = KU + (t * 16 + lm) * KROW + g * 8;
            acc = __builtin_amdgcn_mfma_f32_16x16x32_bf16(qa0, *(const short8v*)kp, acc, 0, 0, 0);
            acc = __builtin_amdgcn_mfma_f32_16x16x32_bf16(qa1, *(const short8v*)(kp + 32), acc, 0, 0, 0);
            sacc[k] = acc;
        }
    }
    __syncthreads();                                                  // 2

    {
        int yw = yr - R; yw = yw < 0 ? 0 : (yw > 96 - KS ? 96 - KS : yw);
        #pragma unroll
        for (int k = 0; k < 3; ++k) {
            int t = wn + 4 * k;
            if (t < NT) {
                int pos = t * 16 + lm;
                int i = pos / CW, j = pos - i * CW;
                int gy = ymin + i;
                int ac = c0 + j;
                int dr = gy - yw;
                int rel_h = gy - yr + KS - 1;
                #pragma unroll
                for (int r = 0; r < 4; ++r) {
                    int xq = x0 + g * 4 + r;
                    int xw = xq - R; xw = xw < 0 ? 0 : (xw > 96 - KS ? 96 - KS : xw);
                    int d = ac - xw;
                    float sv = -1e30f;
                    if (pos < NPOS && (unsigned)dr < (unsigned)KS && (unsigned)d < (unsigned)KS)
                        sv = sacc[k][r] + rpb_s[rel_h * RW + (ac - xq + KS - 1)];
                    S[(mt * 16 + g * 4 + r) * SROW + pos] = sv;
                }
            }
        }
    }
    __syncthreads();                                                  // 3

    {
        int px = w * 4 + g;
        float vals[NT];
        float m = -1e30f;
        #pragma unroll
        for (int k = 0; k < NT; ++k) {
            vals[k] = S[px * SROW + lm + 16 * k];
            m = fmaxf(m, vals[k]);
        }
        #pragma unroll
        for (int off = 1; off < 16; off <<= 1) m = fmaxf(m, __shfl_xor(m, off));
        float sum = 0.f;
        #pragma unroll
        for (int k = 0; k < NT; ++k) { vals[k] = __expf(vals[k] - m); sum += vals[k]; }
        #pragma unroll
        for (int off = 1; off < 16; off <<= 1) sum += __shfl_xor(sum, off);
        float rs = 1.f / sum;
        __hip_bfloat16* pr = (__hip_bfloat16*)((char*)S + (size_t)px * SROW * 4);
        #pragma unroll
        for (int k = 0; k < NT; ++k)
            pr[lm + 16 * k] = __float2bfloat16(vals[k] * rs);
        pr[NKR + lm] = __float2bfloat16(0.f);
    }
    __syncthreads();                                                  // 4

    f32x4 oacc = {0, 0, 0, 0};
    const __hip_bfloat16* pr = (const __hip_bfloat16*)((char*)S + (size_t)(mt * 16 + lm) * SROW * 4);
    #pragma unroll
    for (int kk = 0; kk < NKV / 32; ++kk) {
        short8v pa = *(const short8v*)(pr + kk * 32 + g * 8);
        short8v vb = *(const short8v*)(Vt + (wn * 16 + lm) * VROW + kk * 32 + g * 8);
        oacc = __builtin_amdgcn_mfma_f32_16x16x32_bf16(pa, vb, oacc, 0, 0, 0);
    }
    __hip_bfloat16* ob = featp + (((size_t)b * 98 + yr + 1) * 98 + (x0 + 1)) * 192 + coff + wn * 16 + lm;
    #pragma unroll
    for (int r = 0; r < 4; ++r)
        ob[(size_t)(g * 4 + r) * 192] = __float2bfloat16(oacc[r]);
}

#define NAT3_SMEM (176*72*2 + 64*202*2 + 13*13*4)

__global__ __launch_bounds__(512, 6) void natten_both3_k(
    const __hip_bfloat16* __restrict__ q_b,
    const __hip_bfloat16* __restrict__ k_b,
    const __hip_bfloat16* __restrict__ v0_b,
    const __hip_bfloat16* __restrict__ v1_b,
    const float* __restrict__ rpb0,
    const float* __restrict__ rpb1,
    __hip_bfloat16* __restrict__ featp) {
    __shared__ __align__(16) char smem[NAT3_SMEM];
    int blk = xcd_swz576(blockIdx.x);
    natten_body3<7>(q_b, k_b, v1_b, rpb1, featp, 128, smem, blk);
    __syncthreads();
    natten_body3<3>(q_b, k_b, v0_b, rpb0, featp, 64, smem, blk);
}

// ---------------- fuse conv v8: 32-px strips, 8 waves, lean loop ----------------
__global__ __launch_bounds__(512, 6) void fuse_v8_k(const __hip_bfloat16* __restrict__ featp,
                                                    const __hip_bfloat16* __restrict__ wtp,
                                                    const float* __restrict__ b_fuse,
                                                    float* __restrict__ out) {
    constexpr int AROW = 200;
    __shared__ __hip_bfloat16 Alds[3 * 34 * AROW];
    int tid = threadIdx.x;
    int l = tid & 63, w = tid >> 6;
    int lm = l & 15, g = l >> 4;
    int mt = w >> 2, wn = w & 3;
    int blk = xcd_swz576(blockIdx.x);
    int x0 = (blk % 3) * 32;
    int row = blk / 3;
    int b = row / 96, y = row - b * 96;
    int rem0 = y * 96 + x0;

    const __hip_bfloat16* fbase = featp + (((size_t)b * 98 + y) * 98 + x0) * 192;
    for (int e = tid; e < 3 * 34 * 24; e += 512) {
        int rowidx = e / 24, cc = (e - rowidx * 24) * 8;
        int r = rowidx / 34, xc = rowidx - r * 34;
        short8v v = *(const short8v*)(fbase + ((size_t)r * 98 + xc) * 192 + cc);
        *(short8v*)(&Alds[rowidx * AROW + cc]) = v;
    }
    __syncthreads();

    const __hip_bfloat16* bp = wtp + ((size_t)wn * 54 * 64 + l) * 8;
    f32x4 accA = {0, 0, 0, 0}, accB = {0, 0, 0, 0};
    #pragma unroll
    for (int tap = 0; tap < 9; ++tap) {
        int r = tap / 3, dx = tap % 3;
        const __hip_bfloat16* ap = &Alds[(r * 34 + mt * 16 + lm + dx) * AROW + g * 8];
        #pragma unroll
        for (int kk = 0; kk < 6; ++kk) {
            int ks = tap * 6 + kk;
            short8v a  = *(const short8v*)(ap + kk * 32);
            short8v bv = *(const short8v*)(bp + (size_t)ks * 512);
            if (kk & 1)
                accB = __builtin_amdgcn_mfma_f32_16x16x32_bf16(a, bv, accB, 0, 0, 0);
            else
                accA = __builtin_amdgcn_mfma_f32_16x16x32_bf16(a, bv, accA, 0, 0, 0);
        }
    }
    int o = wn * 16 + lm;
    float bias = b_fuse[o];
    float4 st = { accA[0] + accB[0] + bias, accA[1] + accB[1] + bias,
                  accA[2] + accB[2] + bias, accA[3] + accB[3] + bias };
    *(float4*)(out + (size_t)(b * 64 + o) * HW + rem0 + mt * 16 + g * 4) = st;
}

extern "C" void kernel_launch(void* const* d_in, const int* in_sizes, int n_in,
                              void* d_out, int out_size, void* d_ws, size_t ws_size,
                              hipStream_t stream) {
    const float* past     = (const float*)d_in[0];
    const float* curr     = (const float*)d_in[1];
    const float* w_smooth = (const float*)d_in[2];
    const float* b_smooth = (const float*)d_in[3];
    const float* w_reduce = (const float*)d_in[4];
    const float* b_reduce = (const float*)d_in[5];
    const float* w_v0     = (const float*)d_in[6];
    const float* b_v0     = (const float*)d_in[7];
    const float* w_v1     = (const float*)d_in[8];
    const float* b_v1     = (const float*)d_in[9];
    const float* rpb0     = (const float*)d_in[10];
    const float* rpb1     = (const float*)d_in[11];
    const float* w_fuse   = (const float*)d_in[12];
    const float* b_fuse   = (const float*)d_in[13];
    float* out = (float*)d_out;

    const size_t NF = (size_t)NPIX * 64;
    char* p = (char*)d_ws;
    auto carve = [&](size_t bytes) { char* r = p; p += (bytes + 255) & ~(size_t)255; return r; };
    __hip_bfloat16* featp    = (__hip_bfloat16*)carve((size_t)2 * 98 * 98 * 192 * 2);
    __hip_bfloat16* curr_b   = (__hip_bfloat16*)carve(NF * 2);
    __hip_bfloat16* pg       = (__hip_bfloat16*)carve(NF * 2);
    __hip_bfloat16* past2_b  = (__hip_bfloat16*)carve(NF * 2);
    __hip_bfloat16* v0_b     = (__hip_bfloat16*)carve(NF * 2);
    __hip_bfloat16* v1_b     = (__hip_bfloat16*)carve(NF * 2);
    __hip_bfloat16* wtp      = (__hip_bfloat16*)carve((size_t)64 * 1728 * 2);
    __hip_bfloat16* wr_b     = (__hip_bfloat16*)carve((size_t)64 * 128 * 2);
    __hip_bfloat16* wv0_b    = (__hip_bfloat16*)carve((size_t)64 * 64 * 2);
    __hip_bfloat16* wv1_b    = (__hip_bfloat16*)carve((size_t)64 * 64 * 2);

    dim3 tb(32, 8, 1), tg(HW / 32, 2, 5);
    transprep_k<<<tg, tb, 0, stream>>>(past, curr, w_fuse, w_reduce, w_v0, w_v1,
                                       curr_b, featp, pg, wtp, wr_b, wv0_b, wv1_b);
    smoothrv_k<<<NPIX / 32, 256, 0, stream>>>(pg, w_smooth, b_smooth, wr_b, b_reduce,
                                              wv0_b, wv1_b, b_v0, b_v1,
                                              past2_b, v0_b, v1_b);
    natten_both3_k<<<NPIX / 32, 512, 0, stream>>>(curr_b, past2_b, v0_b, v1_b, rpb0, rpb1, featp);
    fuse_v8_k<<<NPIX / 32, 512, 0, stream>>>(featp, wtp, b_fuse, out);
}

// Round 22
// 69.757 us; speedup vs baseline: 1.0180x; 1.0180x over previous
//
#include <hip/hip_runtime.h>
#include <hip/hip_bf16.h>

#define HW 9216
#define NPIX 18432

typedef __attribute__((ext_vector_type(8))) short short8v;
typedef __attribute__((ext_vector_type(4))) float f32x4;

__device__ __forceinline__ float bf2f(short s) {
    union { unsigned u; float f; } c;
    c.u = ((unsigned)(unsigned short)s) << 16;
    return c.f;
}
__device__ __forceinline__ unsigned short f2bfbits(float f) {
    __hip_bfloat16 h = __float2bfloat16(f);
    return *reinterpret_cast<unsigned short*>(&h);
}

// bijective XCD swizzle for 576-block grids (576 = 8 * 72)
__device__ __forceinline__ int xcd_swz576(int bid) {
    return (bid & 7) * 72 + (bid >> 3);
}

// ---------------- transpose (z<4, ushort4 stores) + weight prep / border zero (z==4) ----------------
__global__ void transprep_k(const float* __restrict__ past, const float* __restrict__ curr,
                            const float* __restrict__ w_fuse, const float* __restrict__ w_reduce,
                            const float* __restrict__ w_v0, const float* __restrict__ w_v1,
                            __hip_bfloat16* __restrict__ curr_b,
                            __hip_bfloat16* __restrict__ featp,
                            __hip_bfloat16* __restrict__ pg,
                            __hip_bfloat16* __restrict__ wtp, __hip_bfloat16* __restrict__ wr_b,
                            __hip_bfloat16* __restrict__ wv0_b, __hip_bfloat16* __restrict__ wv1_b) {
    int z = blockIdx.z;
    if (z < 4) {
        __shared__ float tile[32][33];               // [c_local][px]
        int t = z & 1, b = z >> 1;
        const float* src = t ? curr : past;
        int p0 = blockIdx.x * 32, c0 = blockIdx.y * 32;
        for (int k = threadIdx.y; k < 32; k += 8)
            tile[k][threadIdx.x] = src[(size_t)(b * 64 + c0 + k) * HW + p0 + threadIdx.x];
        __syncthreads();
        int tid = threadIdx.y * 32 + threadIdx.x;
        int px = tid >> 3, cq = tid & 7;
        int pp = p0 + px;
        int cl = cq * 4;
        ushort4 pk;
        pk.x = f2bfbits(tile[cl + 0][px]);
        pk.y = f2bfbits(tile[cl + 1][px]);
        pk.z = f2bfbits(tile[cl + 2][px]);
        pk.w = f2bfbits(tile[cl + 3][px]);
        int c = c0 + cl;
        if (t) {
            *(ushort4*)(curr_b + ((size_t)b * HW + pp) * 64 + c) = pk;
        } else {
            int y = pp / 96, x = pp - (pp / 96) * 96;
            *(ushort4*)(featp + (((size_t)b * 98 + y + 1) * 98 + x + 1) * 192 + c) = pk;
            int g = c >> 3, cg = c & 7;
            *(ushort4*)(pg + (((size_t)b * 8 + g) * HW + pp) * 8 + cg) = pk;
        }
    } else {
        int i = (blockIdx.y * 288 + blockIdx.x) * 256 + threadIdx.y * 32 + threadIdx.x;
        if (i < 110592) {
            int j = i & 7, rest = i >> 3;
            int lm = rest & 15; rest >>= 4;
            int g = rest & 3; rest >>= 2;
            int ks = rest % 54, nt = rest / 54;
            int o = nt * 16 + lm;
            int kg = ks * 32 + g * 8 + j;
            int tap = kg / 192, c = kg - tap * 192;
            wtp[i] = __float2bfloat16(w_fuse[o * 1728 + c * 9 + tap]);
        }
        if (i < 8192) wr_b[i] = __float2bfloat16(w_reduce[i]);
        if (i < 4096) { wv0_b[i] = __float2bfloat16(w_v0[i]); wv1_b[i] = __float2bfloat16(w_v1[i]); }
        if (i < 2 * 98 * 98) {
            int pp = i % (98 * 98);
            int y = pp / 98, x = pp - y * 98;
            if (y == 0 || y == 97 || x == 0 || x == 97) {
                short8v zz = {0, 0, 0, 0, 0, 0, 0, 0};
                short8v* d = (short8v*)(featp + (size_t)i * 192);
                #pragma unroll
                for (int k = 0; k < 24; ++k) d[k] = zz;
            }
        }
    }
}

// ---------------- smooth + reduce + V convs: 32 px/block, 256 threads, 576 blocks ----------------
__global__ __launch_bounds__(256) void smoothrv_k(const __hip_bfloat16* __restrict__ pg,
                                                  const float* __restrict__ w_smooth,
                                                  const float* __restrict__ b_smooth,
                                                  const __hip_bfloat16* __restrict__ wr_b,
                                                  const float* __restrict__ b_reduce,
                                                  const __hip_bfloat16* __restrict__ wv0_b,
                                                  const __hip_bfloat16* __restrict__ wv1_b,
                                                  const float* __restrict__ b_v0,
                                                  const float* __restrict__ b_v1,
                                                  __hip_bfloat16* __restrict__ past2_b,
                                                  __hip_bfloat16* __restrict__ v0_b,
                                                  __hip_bfloat16* __restrict__ v1_b) {
    __shared__ __hip_bfloat16 sm[32][72];
    __shared__ __hip_bfloat16 p2[32][72];
    int tid = threadIdx.x;
    int p0 = blockIdx.x * 32;                  // 32 | 9216: never crosses batch
    int bb = p0 / HW, rem0 = p0 - bb * HW;

    // ---- phase A: smooth; thread = (group g, pixel px) ----
    {
        int g = tid >> 5, px = tid & 31;
        int rem = rem0 + px;
        int y = rem / 96, x = rem - y * 96;
        int gi = g < 4 ? g : g + 1;            // skip (0,0)
        int sy = gi / 3 - 1, sx = gi % 3 - 1;
        const __hip_bfloat16* base = pg + (((size_t)bb * 8 + g) * HW) * 8;
        float v[9][8];
        #pragma unroll
        for (int ky = 0; ky < 3; ++ky) {
            #pragma unroll
            for (int kx = 0; kx < 3; ++kx) {
                int yy = y + ky - 1, xx = x + kx - 1;
                int ys = yy - sy, xs = xx - sx;
                bool ok = (unsigned)yy < 96u && (unsigned)xx < 96u &&
                          (unsigned)ys < 96u && (unsigned)xs < 96u;
                int off = ok ? (ys * 96 + xs) : rem;
                short8v ld = *(const short8v*)(base + (size_t)off * 8);
                float okf = ok ? 1.f : 0.f;
                #pragma unroll
                for (int c = 0; c < 8; ++c)
                    v[ky * 3 + kx][c] = okf * bf2f(ld[c]);
            }
        }
        float acc[8];
        #pragma unroll
        for (int j = 0; j < 8; ++j) acc[j] = b_smooth[g * 8 + j];
        #pragma unroll
        for (int j = 0; j < 8; ++j) {
            const float* wp = w_smooth + (g * 8 + j) * 72;   // wave-uniform -> s_load
            #pragma unroll
            for (int c = 0; c < 8; ++c)
                #pragma unroll
                for (int t = 0; t < 9; ++t)
                    acc[j] += wp[c * 9 + t] * v[t][c];
        }
        short8v pack;
        #pragma unroll
        for (int j = 0; j < 8; ++j) {
            __hip_bfloat16 h = __float2bfloat16(acc[j]);
            pack[j] = *reinterpret_cast<short*>(&h);
        }
        *(short8v*)(&sm[px][g * 8]) = pack;
    }
    __syncthreads();

    // ---- phase B: 1x1 reduce (K=128 over [past | smooth]); 4 waves over 32px x 64ch ----
    int w = tid >> 6, lane = tid & 63;
    int mtile = w >> 1, nbase = (w & 1) * 32;
    int lm = lane & 15, g = lane >> 4;
    int o0 = nbase + lm, o1 = o0 + 16;
    {
        f32x4 acc0 = {0, 0, 0, 0}, acc1 = {0, 0, 0, 0};
        int pixr = rem0 + mtile * 16 + lm;
        const __hip_bfloat16* b0p = wr_b + (size_t)(nbase + lm) * 128 + g * 8;
        const __hip_bfloat16* b1p = b0p + 16 * 128;
        #pragma unroll
        for (int c0 = 0; c0 < 128; c0 += 32) {
            short8v a;
            if (c0 < 64) {
                int gch = (c0 >> 3) + g;
                a = *reinterpret_cast<const short8v*>(
                        pg + (((size_t)bb * 8 + gch) * HW + pixr) * 8);
            } else {
                a = *reinterpret_cast<const short8v*>(&sm[mtile * 16 + lm][g * 8 + (c0 - 64)]);
            }
            short8v b0 = *reinterpret_cast<const short8v*>(b0p + c0);
            short8v b1 = *reinterpret_cast<const short8v*>(b1p + c0);
            acc0 = __builtin_amdgcn_mfma_f32_16x16x32_bf16(a, b0, acc0, 0, 0, 0);
            acc1 = __builtin_amdgcn_mfma_f32_16x16x32_bf16(a, b1, acc1, 0, 0, 0);
        }
        float bias0 = b_reduce[o0], bias1 = b_reduce[o1];
        #pragma unroll
        for (int r = 0; r < 4; ++r) {
            int pl = mtile * 16 + g * 4 + r;
            __hip_bfloat16 h0 = __float2bfloat16(acc0[r] + bias0);
            __hip_bfloat16 h1 = __float2bfloat16(acc1[r] + bias1);
            p2[pl][o0] = h0; p2[pl][o1] = h1;
            past2_b[(size_t)(p0 + pl) * 64 + o0] = h0;
            past2_b[(size_t)(p0 + pl) * 64 + o1] = h1;
        }
    }
    __syncthreads();

    // ---- phase C: both V 1x1 convs from LDS past2 ----
    {
        f32x4 a00 = {0,0,0,0}, a01 = {0,0,0,0}, a10 = {0,0,0,0}, a11 = {0,0,0,0};
        size_t bo = (size_t)(nbase + lm) * 64 + g * 8;
        #pragma unroll
        for (int c0 = 0; c0 < 64; c0 += 32) {
            short8v a   = *reinterpret_cast<const short8v*>(&p2[mtile * 16 + lm][g * 8 + c0]);
            short8v b00 = *reinterpret_cast<const short8v*>(wv0_b + bo + c0);
            short8v b01 = *reinterpret_cast<const short8v*>(wv0_b + bo + 16 * 64 + c0);
            short8v b10 = *reinterpret_cast<const short8v*>(wv1_b + bo + c0);
            short8v b11 = *reinterpret_cast<const short8v*>(wv1_b + bo + 16 * 64 + c0);
            a00 = __builtin_amdgcn_mfma_f32_16x16x32_bf16(a, b00, a00, 0, 0, 0);
            a01 = __builtin_amdgcn_mfma_f32_16x16x32_bf16(a, b01, a01, 0, 0, 0);
            a10 = __builtin_amdgcn_mfma_f32_16x16x32_bf16(a, b10, a10, 0, 0, 0);
            a11 = __builtin_amdgcn_mfma_f32_16x16x32_bf16(a, b11, a11, 0, 0, 0);
        }
        float bi00 = b_v0[o0], bi01 = b_v0[o1], bi10 = b_v1[o0], bi11 = b_v1[o1];
        #pragma unroll
        for (int r = 0; r < 4; ++r) {
            int p = p0 + mtile * 16 + g * 4 + r;
            v0_b[(size_t)p * 64 + o0] = __float2bfloat16(a00[r] + bi00);
            v0_b[(size_t)p * 64 + o1] = __float2bfloat16(a01[r] + bi01);
            v1_b[(size_t)p * 64 + o0] = __float2bfloat16(a10[r] + bi10);
            v1_b[(size_t)p * 64 + o1] = __float2bfloat16(a11[r] + bi11);
        }
    }
}

// ---------------- natten3 body: 2x16-px tile, Q in registers, exact K-tiling ----------------
template <int KS>
__device__ __forceinline__ void natten_body3(
    const __hip_bfloat16* __restrict__ q_b,
    const __hip_bfloat16* __restrict__ k_b,
    const __hip_bfloat16* __restrict__ v_b,
    const float* __restrict__ rpb,
    __hip_bfloat16* __restrict__ featp, int coff, char* smem, int blk) {
    constexpr int R = KS / 2, RW = 2 * KS - 1;
    constexpr int CW = 16 + KS - 1;
    constexpr int RU = KS + 1;
    constexpr int NPOS = RU * CW;
    constexpr int NT = (NPOS + 15) / 16;
    constexpr int NKR = NT * 16;
    constexpr int NKV = ((NPOS + 31) / 32) * 32;
    constexpr int KROW = 72;
    constexpr int VROW = NKV + 10;
    constexpr int SROW = NKR + 4;

    __hip_bfloat16* KU = (__hip_bfloat16*)smem;
    float*          S  = (float*)smem;
    __hip_bfloat16* Vt = (__hip_bfloat16*)(smem + NKR * KROW * 2);
    float*       rpb_s = (float*)((char*)Vt + 64 * VROW * 2);

    int x0 = (blk % 6) * 16;
    int rp = blk / 6;
    int b = rp / 48, yp = (rp - b * 48) * 2;
    int ymin = yp - R; ymin = ymin < 0 ? 0 : (ymin > 96 - KS ? 96 - KS : ymin);
    int c0 = x0 - R;   c0 = c0 < 0 ? 0 : (c0 > 96 - KS ? 96 - KS : c0);
    int tid = threadIdx.x;
    size_t plane = (size_t)b * HW;

    int l = tid & 63, w = tid >> 6;
    int lm = l & 15, g = l >> 4;
    int mt = w >> 2, wn = w & 3;
    int yr = yp + mt;

    const __hip_bfloat16* qp = q_b + (plane + yr * 96 + x0 + lm) * 64 + g * 8;
    short8v qa0 = *(const short8v*)qp;
    short8v qa1 = *(const short8v*)(qp + 32);

    for (int i = tid; i < RW * RW; i += 512) rpb_s[i] = rpb[i];
    for (int pos = tid >> 3; pos < NKR; pos += 64) {
        int c8 = (tid & 7) * 8;
        short8v val = {0, 0, 0, 0, 0, 0, 0, 0};
        if (pos < NPOS) {
            int i = pos / CW, j = pos - i * CW;
            int gy = ymin + i; gy = gy > 95 ? 95 : gy;
            int gx = c0 + j;   gx = gx > 95 ? 95 : gx;
            val = *(const short8v*)(k_b + (plane + gy * 96 + gx) * 64 + c8);
        }
        *(short8v*)(KU + pos * KROW + c8) = val;
    }
    for (int pos = tid >> 3; pos < NKV; pos += 64) {
        int c8 = (tid & 7) * 8;
        short8v val = {0, 0, 0, 0, 0, 0, 0, 0};
        if (pos < NPOS) {
            int i = pos / CW, j = pos - i * CW;
            int gy = ymin + i; gy = gy > 95 ? 95 : gy;
            int gx = c0 + j;   gx = gx > 95 ? 95 : gx;
            val = *(const short8v*)(v_b + (plane + gy * 96 + gx) * 64 + c8);
        }
        #pragma unroll
        for (int j = 0; j < 8; ++j)
            *((short*)Vt + (c8 + j) * VROW + pos) = val[j];
    }
    __syncthreads();                                                  // 1

    f32x4 sacc[3];
    #pragma unroll
    for (int k = 0; k < 3; ++k) {
        int t = wn + 4 * k;
        if (t < NT) {
            f32x4 acc = {0, 0, 0, 0};
            const __hip_bfloat16* kp = KU + (t * 16 + lm) * KROW + g * 8;
            acc = __builtin_amdgcn_mfma_f32_16x16x32_bf16(qa0, *(const short8v*)kp, acc, 0, 0, 0);
            acc = __builtin_amdgcn_mfma_f32_16x16x32_bf16(qa1, *(const short8v*)(kp + 32), acc, 0, 0, 0);
            sacc[k] = acc;
        }
    }
    __syncthreads();                                                  // 2

    {
        int yw = yr - R; yw = yw < 0 ? 0 : (yw > 96 - KS ? 96 - KS : yw);
        #pragma unroll
        for (int k = 0; k < 3; ++k) {
            int t = wn + 4 * k;
            if (t < NT) {
                int pos = t * 16 + lm;
                int i = pos / CW, j = pos - i * CW;
                int gy = ymin + i;
                int ac = c0 + j;
                int dr = gy - yw;
                int rel_h = gy - yr + KS - 1;
                #pragma unroll
                for (int r = 0; r < 4; ++r) {
                    int xq = x0 + g * 4 + r;
                    int xw = xq - R; xw = xw < 0 ? 0 : (xw > 96 - KS ? 96 - KS : xw);
                    int d = ac - xw;
                    float sv = -1e30f;
                    if (pos < NPOS && (unsigned)dr < (unsigned)KS && (unsigned)d < (unsigned)KS)
                        sv = sacc[k][r] + rpb_s[rel_h * RW + (ac - xq + KS - 1)];
                    S[(mt * 16 + g * 4 + r) * SROW + pos] = sv;
                }
            }
        }
    }
    __syncthreads();                                                  // 3

    {
        int px = w * 4 + g;
        float vals[NT];
        float m = -1e30f;
        #pragma unroll
        for (int k = 0; k < NT; ++k) {
            vals[k] = S[px * SROW + lm + 16 * k];
            m = fmaxf(m, vals[k]);
        }
        #pragma unroll
        for (int off = 1; off < 16; off <<= 1) m = fmaxf(m, __shfl_xor(m, off));
        float sum = 0.f;
        #pragma unroll
        for (int k = 0; k < NT; ++k) { vals[k] = __expf(vals[k] - m); sum += vals[k]; }
        #pragma unroll
        for (int off = 1; off < 16; off <<= 1) sum += __shfl_xor(sum, off);
        float rs = 1.f / sum;
        __hip_bfloat16* pr = (__hip_bfloat16*)((char*)S + (size_t)px * SROW * 4);
        #pragma unroll
        for (int k = 0; k < NT; ++k)
            pr[lm + 16 * k] = __float2bfloat16(vals[k] * rs);
        pr[NKR + lm] = __float2bfloat16(0.f);
    }
    __syncthreads();                                                  // 4

    f32x4 oacc = {0, 0, 0, 0};
    const __hip_bfloat16* pr = (const __hip_bfloat16*)((char*)S + (size_t)(mt * 16 + lm) * SROW * 4);
    #pragma unroll
    for (int kk = 0; kk < NKV / 32; ++kk) {
        short8v pa = *(const short8v*)(pr + kk * 32 + g * 8);
        short8v vb = *(const short8v*)(Vt + (wn * 16 + lm) * VROW + kk * 32 + g * 8);
        oacc = __builtin_amdgcn_mfma_f32_16x16x32_bf16(pa, vb, oacc, 0, 0, 0);
    }
    __hip_bfloat16* ob = featp + (((size_t)b * 98 + yr + 1) * 98 + (x0 + 1)) * 192 + coff + wn * 16 + lm;
    #pragma unroll
    for (int r = 0; r < 4; ++r)
        ob[(size_t)(g * 4 + r) * 192] = __float2bfloat16(oacc[r]);
}

#define NAT3_SMEM (176*72*2 + 64*202*2 + 13*13*4)

__global__ __launch_bounds__(512, 6) void natten_both3_k(
    const __hip_bfloat16* __restrict__ q_b,
    const __hip_bfloat16* __restrict__ k_b,
    const __hip_bfloat16* __restrict__ v0_b,
    const __hip_bfloat16* __restrict__ v1_b,
    const float* __restrict__ rpb0,
    const float* __restrict__ rpb1,
    __hip_bfloat16* __restrict__ featp) {
    __shared__ __align__(16) char smem[NAT3_SMEM];
    int blk = xcd_swz576(blockIdx.x);
    natten_body3<7>(q_b, k_b, v1_b, rpb1, featp, 128, smem, blk);
    __syncthreads();
    natten_body3<3>(q_b, k_b, v0_b, rpb0, featp, 64, smem, blk);
}

// ---------------- fuse conv v8: 32-px strips, 8 waves, lean loop ----------------
__global__ __launch_bounds__(512, 6) void fuse_v8_k(const __hip_bfloat16* __restrict__ featp,
                                                    const __hip_bfloat16* __restrict__ wtp,
                                                    const float* __restrict__ b_fuse,
                                                    float* __restrict__ out) {
    constexpr int AROW = 200;
    __shared__ __hip_bfloat16 Alds[3 * 34 * AROW];
    int tid = threadIdx.x;
    int l = tid & 63, w = tid >> 6;
    int lm = l & 15, g = l >> 4;
    int mt = w >> 2, wn = w & 3;
    int blk = xcd_swz576(blockIdx.x);
    int x0 = (blk % 3) * 32;
    int row = blk / 3;
    int b = row / 96, y = row - b * 96;
    int rem0 = y * 96 + x0;

    const __hip_bfloat16* fbase = featp + (((size_t)b * 98 + y) * 98 + x0) * 192;
    for (int e = tid; e < 3 * 34 * 24; e += 512) {
        int rowidx = e / 24, cc = (e - rowidx * 24) * 8;
        int r = rowidx / 34, xc = rowidx - r * 34;
        short8v v = *(const short8v*)(fbase + ((size_t)r * 98 + xc) * 192 + cc);
        *(short8v*)(&Alds[rowidx * AROW + cc]) = v;
    }
    __syncthreads();

    const __hip_bfloat16* bp = wtp + ((size_t)wn * 54 * 64 + l) * 8;
    f32x4 accA = {0, 0, 0, 0}, accB = {0, 0, 0, 0};
    #pragma unroll
    for (int tap = 0; tap < 9; ++tap) {
        int r = tap / 3, dx = tap % 3;
        const __hip_bfloat16* ap = &Alds[(r * 34 + mt * 16 + lm + dx) * AROW + g * 8];
        #pragma unroll
        for (int kk = 0; kk < 6; ++kk) {
            int ks = tap * 6 + kk;
            short8v a  = *(const short8v*)(ap + kk * 32);
            short8v bv = *(const short8v*)(bp + (size_t)ks * 512);
            if (kk & 1)
                accB = __builtin_amdgcn_mfma_f32_16x16x32_bf16(a, bv, accB, 0, 0, 0);
            else
                accA = __builtin_amdgcn_mfma_f32_16x16x32_bf16(a, bv, accA, 0, 0, 0);
        }
    }
    int o = wn * 16 + lm;
    float bias = b_fuse[o];
    float4 st = { accA[0] + accB[0] + bias, accA[1] + accB[1] + bias,
                  accA[2] + accB[2] + bias, accA[3] + accB[3] + bias };
    *(float4*)(out + (size_t)(b * 64 + o) * HW + rem0 + mt * 16 + g * 4) = st;
}

extern "C" void kernel_launch(void* const* d_in, const int* in_sizes, int n_in,
                              void* d_out, int out_size, void* d_ws, size_t ws_size,
                              hipStream_t stream) {
    const float* past     = (const float*)d_in[0];
    const float* curr     = (const float*)d_in[1];
    const float* w_smooth = (const float*)d_in[2];
    const float* b_smooth = (const float*)d_in[3];
    const float* w_reduce = (const float*)d_in[4];
    const float* b_reduce = (const float*)d_in[5];
    const float* w_v0     = (const float*)d_in[6];
    const float* b_v0     = (const float*)d_in[7];
    const float* w_v1     = (const float*)d_in[8];
    const float* b_v1     = (const float*)d_in[9];
    const float* rpb0     = (const float*)d_in[10];
    const float* rpb1     = (const float*)d_in[11];
    const float* w_fuse   = (const float*)d_in[12];
    const float* b_fuse   = (const float*)d_in[13];
    float* out = (float*)d_out;

    const size_t NF = (size_t)NPIX * 64;
    char* p = (char*)d_ws;
    auto carve = [&](size_t bytes) { char* r = p; p += (bytes + 255) & ~(size_t)255; return r; };
    __hip_bfloat16* featp    = (__hip_bfloat16*)carve((size_t)2 * 98 * 98 * 192 * 2);
    __hip_bfloat16* curr_b   = (__hip_bfloat16*)carve(NF * 2);
    __hip_bfloat16* pg       = (__hip_bfloat16*)carve(NF * 2);
    __hip_bfloat16* past2_b  = (__hip_bfloat16*)carve(NF * 2);
    __hip_bfloat16* v0_b     = (__hip_bfloat16*)carve(NF * 2);
    __hip_bfloat16* v1_b     = (__hip_bfloat16*)carve(NF * 2);
    __hip_bfloat16* wtp      = (__hip_bfloat16*)carve((size_t)64 * 1728 * 2);
    __hip_bfloat16* wr_b     = (__hip_bfloat16*)carve((size_t)64 * 128 * 2);
    __hip_bfloat16* wv0_b    = (__hip_bfloat16*)carve((size_t)64 * 64 * 2);
    __hip_bfloat16* wv1_b    = (__hip_bfloat16*)carve((size_t)64 * 64 * 2);

    dim3 tb(32, 8, 1), tg(HW / 32, 2, 5);
    transprep_k<<<tg, tb, 0, stream>>>(past, curr, w_fuse, w_reduce, w_v0, w_v1,
                                       curr_b, featp, pg, wtp, wr_b, wv0_b, wv1_b);
    smoothrv_k<<<NPIX / 32, 256, 0, stream>>>(pg, w_smooth, b_smooth, wr_b, b_reduce,
                                              wv0_b, wv1_b, b_v0, b_v1,
                                              past2_b, v0_b, v1_b);
    natten_both3_k<<<NPIX / 32, 512, 0, stream>>>(curr_b, past2_b, v0_b, v1_b, rpb0, rpb1, featp);
    fuse_v8_k<<<NPIX / 32, 512, 0, stream>>>(featp, wtp, b_fuse, out);
}